// Round 9
// baseline (1313.614 us; speedup 1.0000x reference)
//
#include <hip/hip_runtime.h>
#include <math.h>

// Persistent-kernel ResonatorABC scan — tagged dataflow + adaptive-window exact select.
// Grid: 128 WGs x 256 threads (4 waves). WG w owns features [8w,8w+8) for ALL
// 128 rows; each thread owns 4 (b,f) elements: b = rg+32k, f = 8w+fl.
// Round-9 theme: cut per-step overhead. Barriers 11->7 (direct partial reads,
// fused wave0 scan+locate); per-step min/max removed via adaptive pow2-width
// bin window carried across steps (exact: clamped partition still order-
// consistent; refine fallback unchanged); poll backoff cuts fabric traffic.

#define T_STEPS 128
#define B_DIM   128
#define F_DIM   1024
#define NWG     128
#define NTH     256
#define BF      (B_DIM * F_DIM)

typedef unsigned long long ull;

__device__ __forceinline__ ull ld64(const ull* p) {
  return __hip_atomic_load(p, __ATOMIC_RELAXED, __HIP_MEMORY_SCOPE_AGENT);
}
__device__ __forceinline__ void st64(ull* p, ull v) {
  __hip_atomic_store(p, v, __ATOMIC_RELAXED, __HIP_MEMORY_SCOPE_AGENT);
}

extern "C" __global__ void __launch_bounds__(NTH)
ResonatorABC_82094004896068_kernel(
    const float* __restrict__ in_re, const float* __restrict__ in_im,
    const float* __restrict__ r_re_p, const float* __restrict__ r_im_p,
    const float* __restrict__ alpha_map, const float* __restrict__ lambda_map,
    float* __restrict__ out, ull* __restrict__ ws)
{
  const int tid  = threadIdx.x;
  const int wg   = blockIdx.x;
  const int fl   = tid & 7;         // feature-local index
  const int rg   = tid >> 3;        // row-group base (0..31); rows rg+32k
  const int f    = (wg << 3) + fl;  // global feature
  const int wid  = tid >> 6;        // wave id (0..3)
  const int lane = tid & 63;

  ull* score64 = ws;                // [B][F] {tag|score_bits}
  ull* taubox  = ws + BF;           // [128 consumers][256 slots] {tag|tau_bits}

  __shared__ __align__(16) float pamp[4][8][4];   // wave partials: amp, amp2, unit_re, unit_im
  __shared__ __align__(16) float pev[4][8][2];    // wave partials: evB, evC
  __shared__ __align__(16) unsigned h[1024];      // histogram
  __shared__ unsigned wsum[4];                    // refine cross-wave scan
  __shared__ unsigned win[2];                     // adaptive bin window [lo,hi] (bits)
  __shared__ unsigned tbin[4], tbase[4], tcnt[4]; // located rank bins
  __shared__ unsigned lcnt[4];                    // list counters
  __shared__ unsigned lists[4][256];              // extracted bin values
  __shared__ unsigned resv[4], resf[4];           // resolved rank values/flags
  __shared__ unsigned rmm[2];                     // refine min/max
  __shared__ unsigned t2[3];                      // refine located bin/base/cnt
  __shared__ float tauLds[256];                   // gathered taus

  const float af = fminf(fmaxf(0.97f + 0.05f * tanhf(alpha_map[f]), 0.90f), 0.995f);
  const float lf = fminf(fmaxf(0.95f + 0.05f * tanhf(lambda_map[f]), 0.90f), 0.995f);
  const float rr = r_re_p[f];
  const float ri = r_im_p[f];
  const float c002 = cosf(0.02f);
  const float s002 = sinf(0.02f);

  float X_re[4] = {0.f,0.f,0.f,0.f}, X_im[4] = {0.f,0.f,0.f,0.f};
  float sA[4] = {0.f,0.f,0.f,0.f}, sB[4] = {0.f,0.f,0.f,0.f}, sC[4] = {0.f,0.f,0.f,0.f};
  float mu = 0.f, var = 0.01f, theta = 0.1f, ema_re = 0.f, ema_im = 0.f;

  int idx[4];
  float ur[4], ui[4];
  #pragma unroll
  for (int k = 0; k < 4; ++k) {
    idx[k] = (rg + 32 * k) * F_DIM + f;
    ur[k] = in_re[idx[k]];
    ui[k] = in_im[idx[k]];
  }

  const unsigned KR[4] = {255u, 256u, 767u, 768u};

  if (tid == 0) { win[0] = 0x3E000000u; win[1] = 0x42000000u; }  // floats [0.125,32]; score>=0.5 at t=0
  __syncthreads();

  for (int t = 0; t < T_STEPS; ++t) {
    const ull want = (ull)(t + 1);

    *(uint4*)&h[4 * tid] = make_uint4(0u, 0u, 0u, 0u);

    // ---------------- Phase 1: elementwise + B-reduced stats + score ----------------
    float Xm_re[4], Xm_im[4], proj[4], amp[4], score[4];
    float a0 = 0.f, a1 = 0.f, a2 = 0.f, a3 = 0.f;
    #pragma unroll
    for (int k = 0; k < 4; ++k) {
      Xm_re[k] = af * X_re[k] + ur[k];
      Xm_im[k] = af * X_im[k] + ui[k];
      float amp2 = Xm_re[k] * Xm_re[k] + Xm_im[k] * Xm_im[k];
      amp[k] = sqrtf(amp2);
      float invamp = (amp[k] > 0.f) ? (1.0f / amp[k]) : 0.f;
      float un_re = (amp[k] > 0.f) ? (Xm_re[k] * invamp) : 1.0f;  // angle(0)=0 -> unit=1
      float un_im = Xm_im[k] * invamp;
      proj[k] = Xm_re[k] * rr + Xm_im[k] * ri;                    // Re(X_mid*conj(r))
      sA[k] = lf * sA[k] + proj[k];
      out[t * BF + idx[k]] = sA[k];
      a0 += amp[k]; a1 += amp2; a2 += un_re; a3 += un_im;
    }
    #pragma unroll
    for (int m = 8; m < 64; m <<= 1) {
      a0 += __shfl_xor(a0, m);
      a1 += __shfl_xor(a1, m);
      a2 += __shfl_xor(a2, m);
      a3 += __shfl_xor(a3, m);
    }
    if (lane < 8) { *(float4*)&pamp[wid][lane][0] = make_float4(a0, a1, a2, a3); }
    __syncthreads();                                   // B1
    float4 P0 = *(const float4*)&pamp[0][fl][0];
    float4 P1 = *(const float4*)&pamp[1][fl][0];
    float4 P2 = *(const float4*)&pamp[2][fl][0];
    float4 P3 = *(const float4*)&pamp[3][fl][0];
    float S0 = P0.x + P1.x + P2.x + P3.x;
    float S1 = P0.y + P1.y + P2.y + P3.y;
    float S2 = P0.z + P1.z + P2.z + P3.z;
    float S3 = P0.w + P1.w + P2.w + P3.w;
    float m1 = S0 * 0.0078125f;
    float m2 = S1 * 0.0078125f;
    mu = 0.9f * mu + 0.1f * m1;
    float vm = m2 - 2.f * mu * m1 + mu * mu;
    vm = fmaxf(vm, 0.f);
    var = 0.9f * var + 0.1f * vm;
    ema_re = 0.9f * ema_re + 0.1f * (S2 * 0.0078125f);
    ema_im = 0.9f * ema_im + 0.1f * (S3 * 0.0078125f);
    float plv = sqrtf(ema_re * ema_re + ema_im * ema_im);
    float sden = sqrtf(var) + 1e-3f;
    #pragma unroll
    for (int k = 0; k < 4; ++k) {
      float zs = (amp[k] - mu) / sden;
      score[k] = amp[k] + 0.5f * fabsf(zs) + 0.5f * (1.0f - plv);
      st64(&score64[idx[k]], (want << 32) | (ull)__float_as_uint(score[k]));
    }

    // prefetch next-step inputs
    float ur_n[4] = {0.f,0.f,0.f,0.f}, ui_n[4] = {0.f,0.f,0.f,0.f};
    if (t + 1 < T_STEPS) {
      #pragma unroll
      for (int k = 0; k < 4; ++k) {
        ur_n[k] = in_re[(t + 1) * BF + idx[k]];
        ui_n[k] = in_im[(t + 1) * BF + idx[k]];
      }
    }

    // window parameters (uniform; written by wave0 last step, many barriers ago)
    const unsigned wlo = win[0], whi = win[1];
    const unsigned range = whi - wlo + 1u;           // whi>wlo always
    int shift = (range <= 1024u) ? 0 : (22 - __clz(range - 1u));
    if (shift < 0) shift = 0;
    const unsigned maxbin = (range - 1u) >> shift;

    // ---------------- Phase 2: poll scores (backoff), bin, exact select ----------------
    unsigned uval[4], bin[4];
    {
      const ull* sp0 = &score64[wg * F_DIM + tid];
      ull v[4]; bool ok[4] = {false, false, false, false};
      int remaining = 4;
      while (remaining) {
        #pragma unroll
        for (int k = 0; k < 4; ++k) if (!ok[k]) v[k] = ld64(sp0 + 256 * k);
        #pragma unroll
        for (int k = 0; k < 4; ++k) {
          if (!ok[k] && (v[k] >> 32) == want) { ok[k] = true; uval[k] = (unsigned)v[k]; --remaining; }
        }
        if (remaining) __builtin_amdgcn_s_sleep(4);
      }
    }
    #pragma unroll
    for (int k = 0; k < 4; ++k) {
      unsigned uc = min(max(uval[k], wlo), whi);
      bin[k] = (uc - wlo) >> shift;
      atomicAdd(&h[bin[k]], 1u);
    }
    if (tid >= 64 && tid < 68) { lcnt[tid - 64] = 0u; resf[tid - 64] = 0u; }
    __syncthreads();                                   // B2

    if (wid == 0) {   // fused scan + locate + window update (16 bins/lane in regs)
      uint4 q0 = *(const uint4*)&h[16 * lane +  0];
      uint4 q1 = *(const uint4*)&h[16 * lane +  4];
      uint4 q2 = *(const uint4*)&h[16 * lane +  8];
      uint4 q3 = *(const uint4*)&h[16 * lane + 12];
      unsigned c16[16] = {q0.x,q0.y,q0.z,q0.w, q1.x,q1.y,q1.z,q1.w,
                          q2.x,q2.y,q2.z,q2.w, q3.x,q3.y,q3.z,q3.w};
      unsigned s16 = 0;
      #pragma unroll
      for (int i = 0; i < 16; ++i) s16 += c16[i];
      unsigned incl = s16;
      #pragma unroll
      for (int d = 1; d < 64; d <<= 1) {
        unsigned vv = __shfl_up(incl, d);
        if (lane >= d) incl += vv;
      }
      unsigned excl = incl - s16;
      // locate the 4 rank bins (each rank lies in exactly one lane's stripe)
      unsigned bacc = excl;
      #pragma unroll
      for (int i = 0; i < 16; ++i) {
        unsigned c = c16[i];
        if (c) {
          #pragma unroll
          for (int r = 0; r < 4; ++r) {
            if (bacc <= KR[r] && KR[r] < bacc + c) {
              tbin[r] = 16 * lane + i; tbase[r] = bacc; tcnt[r] = c;
            }
          }
        }
        bacc += c;
      }
      // occupied span -> next window
      int fi = 16, li = -1;
      #pragma unroll
      for (int i = 0; i < 16; ++i) if (c16[i]) { if (fi == 16) fi = i; li = i; }
      unsigned long long occ = __ballot(s16 > 0);
      int flane = __builtin_ctzll(occ);
      int llane = 63 - __builtin_clzll(occ);
      int fin = __shfl(fi, flane);
      int lin = __shfl(li, llane);
      if (lane == 0) {
        unsigned first_bin = (unsigned)(16 * flane + fin);
        unsigned last_bin  = (unsigned)(16 * llane + lin);
        unsigned nlo, nhi;
        if (first_bin == 0u) {
          unsigned w4 = range >> 2;
          nlo = (wlo > w4) ? (wlo - w4) : 0u;
        } else {
          nlo = wlo + ((first_bin - 1u) << shift);
        }
        if (last_bin >= maxbin) {
          ull tt = (ull)whi + (ull)(range >> 2);
          nhi = (tt > 0x7F7FFFFFull) ? 0x7F7FFFFFu : (unsigned)tt;
        } else {
          ull tt = (ull)wlo + (((ull)(last_bin + 2u)) << shift) - 1ull;   // +1 bin slack
          nhi = (tt > 0x7F7FFFFFull) ? 0x7F7FFFFFu : (unsigned)tt;
        }
        win[0] = nlo; win[1] = nhi;
      }
    }
    __syncthreads();                                   // B3

    // build candidate lists (dedup: first list of each distinct bin; tbin non-decreasing)
    {
      unsigned b0 = tbin[0], b1 = tbin[1], b2 = tbin[2], b3 = tbin[3];
      #pragma unroll
      for (int k = 0; k < 4; ++k) {
        unsigned bk = bin[k], uv = uval[k];
        if (bk == b0) { unsigned s = atomicAdd(&lcnt[0], 1u); if (s < 256u) lists[0][s] = uv; }
        else if (bk == b1 && b1 != b0) { unsigned s = atomicAdd(&lcnt[1], 1u); if (s < 256u) lists[1][s] = uv; }
        else if (bk == b2 && b2 != b1) { unsigned s = atomicAdd(&lcnt[2], 1u); if (s < 256u) lists[2][s] = uv; }
        else if (bk == b3 && b3 != b2) { unsigned s = atomicAdd(&lcnt[3], 1u); if (s < 256u) lists[3][s] = uv; }
      }
    }
    __syncthreads();                                   // B4

    {   // wave j resolves rank j
      const int j = wid;
      int src = j;
      while (src > 0 && tbin[src - 1] == tbin[j]) --src;
      unsigned c = tcnt[j];
      if (c <= 256u) {
        unsigned kk = KR[j] - tbase[j];
        for (int bi = 0; bi < (int)c; bi += 64) {
          int i = bi + lane;
          if (i < (int)c) {
            unsigned e = lists[src][i];
            unsigned r = 0;
            for (int q = 0; q < (int)c; ++q) {
              unsigned x = lists[src][q];
              r += (x < e || (x == e && q < i)) ? 1u : 0u;
            }
            if (r == kk) { resv[j] = e; resf[j] = 1u; }
          }
        }
      }
    }
    __syncthreads();                                   // B5

    // rare exact refine for any unresolved rank (degenerate duplicate-heavy bins)
    for (int j = 0; j < 4; ++j) {
      if (resf[j]) continue;   // uniform
      bool inj[4];
      #pragma unroll
      for (int k = 0; k < 4; ++k) inj[k] = (bin[k] == tbin[j]);
      unsigned krem = KR[j] - tbase[j];
      for (int iter = 0; iter < 40; ++iter) {
        if (tid == 0) { rmm[0] = 0xFFFFFFFFu; rmm[1] = 0u; }
        __syncthreads();
        #pragma unroll
        for (int k = 0; k < 4; ++k)
          if (inj[k]) { atomicMin(&rmm[0], uval[k]); atomicMax(&rmm[1], uval[k]); }
        __syncthreads();
        unsigned wlo2 = rmm[0], whi2 = rmm[1];
        if (wlo2 == whi2) { if (tid == 0) { resv[j] = wlo2; resf[j] = 1u; } __syncthreads(); break; }
        *(uint4*)&h[4 * tid] = make_uint4(0u, 0u, 0u, 0u);
        __syncthreads();
        ull rng2 = (ull)whi2 - (ull)wlo2 + 1ull;
        ull inv2 = (1ull << 40) / rng2;
        unsigned nb[4];
        #pragma unroll
        for (int k = 0; k < 4; ++k) {
          nb[k] = inj[k] ? (unsigned)((((ull)(uval[k] - wlo2)) * inv2) >> 30) : 0u;
          if (inj[k]) atomicAdd(&h[nb[k]], 1u);
        }
        __syncthreads();
        uint4 hc2 = *(const uint4*)&h[4 * tid];
        unsigned s42 = hc2.x + hc2.y + hc2.z + hc2.w;
        unsigned incl2 = s42;
        #pragma unroll
        for (int d = 1; d < 64; d <<= 1) {
          unsigned vv = __shfl_up(incl2, d);
          if (lane >= d) incl2 += vv;
        }
        if (lane == 63) wsum[wid] = incl2;
        if (tid == 0) lcnt[0] = 0u;
        __syncthreads();
        unsigned woff2 = 0u;
        for (int w = 0; w < 4; ++w) if (w < wid) woff2 += wsum[w];
        unsigned gexcl2 = woff2 + incl2 - s42;
        unsigned cv2[4] = {hc2.x, hc2.y, hc2.z, hc2.w};
        unsigned bb2[4];
        bb2[0] = gexcl2; bb2[1] = bb2[0] + cv2[0]; bb2[2] = bb2[1] + cv2[1]; bb2[3] = bb2[2] + cv2[2];
        #pragma unroll
        for (int i = 0; i < 4; ++i) {
          if (cv2[i] > 0u && bb2[i] <= krem && krem < bb2[i] + cv2[i]) {
            t2[0] = 4 * tid + i; t2[1] = bb2[i]; t2[2] = cv2[i];
          }
        }
        __syncthreads();
        unsigned nbin = t2[0], nbase = t2[1], ncnt = t2[2];
        bool newin[4];
        #pragma unroll
        for (int k = 0; k < 4; ++k) newin[k] = inj[k] && (nb[k] == nbin);
        if (ncnt <= 256u) {
          #pragma unroll
          for (int k = 0; k < 4; ++k)
            if (newin[k]) { unsigned s = atomicAdd(&lcnt[0], 1u); if (s < 256u) lists[0][s] = uval[k]; }
          __syncthreads();
          if (wid == 0) {
            unsigned kk2 = krem - nbase;
            for (int bi = 0; bi < (int)ncnt; bi += 64) {
              int i = bi + lane;
              if (i < (int)ncnt) {
                unsigned e = lists[0][i];
                unsigned r = 0;
                for (int q = 0; q < (int)ncnt; ++q) {
                  unsigned x = lists[0][q];
                  r += (x < e || (x == e && q < i)) ? 1u : 0u;
                }
                if (r == kk2) { resv[j] = e; resf[j] = 1u; }
              }
            }
          }
          __syncthreads();
          break;
        }
        #pragma unroll
        for (int k = 0; k < 4; ++k) inj[k] = newin[k];
        krem -= nbase;
      }
    }

    // ---------------- tau publish: fan out to all 128 consumer mailboxes ----------
    {
      float s255 = __uint_as_float(resv[0]);
      float s256 = __uint_as_float(resv[1]);
      float s767 = __uint_as_float(resv[2]);
      float s768 = __uint_as_float(resv[3]);
      float tb = 0.75f * s767 + 0.25f * s768;           // quantile(score, .75)
      float tc = -(0.75f * s256 + 0.25f * s255);        // quantile(-score, .75)
      int c = tid & 127;
      ull w = (tid < 128)
            ? ((want << 32) | (ull)__float_as_uint(tb))
            : ((want << 32) | (ull)__float_as_uint(tc));
      int slot = (tid < 128) ? wg : (128 + wg);
      st64(&taubox[(ull)c * 256 + slot], w);
    }

    // ---------------- tau gather: poll OWN mailbox (sole reader) -> LDS ----------
    {
      const ull* src = &taubox[(ull)wg * 256 + tid];
      ull v2 = ld64(src);
      while ((v2 >> 32) != want) { __builtin_amdgcn_s_sleep(2); v2 = ld64(src); }
      tauLds[tid] = __uint_as_float((unsigned)v2);
    }
    __syncthreads();                                   // B6

    // ---------------- Phase 3: gates, s-updates, events, theta/corr, reentry ----------
    float gB[4];
    float e0 = 0.f, e1 = 0.f;
    #pragma unroll
    for (int k = 0; k < 4; ++k) {
      float tb = tauLds[rg + 32 * k];
      float tc = tauLds[128 + rg + 32 * k];
      float sc = score[k];
      gB[k] = 1.0f / (1.0f + expf(-5.0f * (sc - tb)));
      float gC = 1.0f / (1.0f + expf(-5.0f * (-sc - tc)));
      sB[k] = lf * sB[k] + proj[k] * gB[k];
      sC[k] = lf * sC[k] + proj[k] * gC;
      e0 += (sB[k] >= theta) ? 1.0f : 0.0f;
      e1 += (sC[k] >= theta) ? 1.0f : 0.0f;
    }
    #pragma unroll
    for (int m = 8; m < 64; m <<= 1) {
      e0 += __shfl_xor(e0, m);
      e1 += __shfl_xor(e1, m);
    }
    if (lane < 8) { pev[wid][lane][0] = e0; pev[wid][lane][1] = e1; }
    __syncthreads();                                   // B7
    float2 E0 = *(const float2*)&pev[0][fl][0];
    float2 E1 = *(const float2*)&pev[1][fl][0];
    float2 E2 = *(const float2*)&pev[2][fl][0];
    float2 E3 = *(const float2*)&pev[3][fl][0];
    float cB = E0.x + E1.x + E2.x + E3.x;
    float cC = E0.y + E1.y + E2.y + E3.y;
    float th1 = theta + 0.01f * (cB * 0.0078125f) - 0.01f * (cC * 0.0078125f);
    theta = fminf(fmaxf(th1 - 0.01f * (th1 - 0.1f), 0.01f), 10.0f);
    bool corr = (cB > 0.f);
    #pragma unroll
    for (int k = 0; k < 4; ++k) {
      float fac_re = corr ? (c002 + 0.1f * gB[k]) : 1.0f;
      float fac_im = corr ? s002 : 0.0f;
      X_re[k] = Xm_re[k] * fac_re - Xm_im[k] * fac_im;
      X_im[k] = Xm_re[k] * fac_im + Xm_im[k] * fac_re;
      ur[k] = ur_n[k]; ui[k] = ui_n[k];
    }
  }
}

extern "C" void kernel_launch(void* const* d_in, const int* in_sizes, int n_in,
                              void* d_out, int out_size, void* d_ws, size_t ws_size,
                              hipStream_t stream) {
  const float* in_re = (const float*)d_in[0];
  const float* in_im = (const float*)d_in[1];
  const float* r_re  = (const float*)d_in[2];
  const float* r_im  = (const float*)d_in[3];
  const float* amap  = (const float*)d_in[4];
  const float* lmap  = (const float*)d_in[5];
  float* out = (float*)d_out;
  ull* ws = (ull*)d_ws;
  // zero all tag words (score + mailboxes) so no stale tag can match
  hipMemsetAsync(d_ws, 0, (size_t)(BF + 128 * 256) * 8, stream);
  hipLaunchKernelGGL(ResonatorABC_82094004896068_kernel,
                     dim3(NWG), dim3(NTH), 0, stream,
                     in_re, in_im, r_re, r_im, amap, lmap, out, ws);
}